// Round 5
// baseline (113.880 us; speedup 1.0000x reference)
//
#include <hip/hip_runtime.h>

// PopulationLayer: lateral = pa @ (W with zeroed diag); v_new = exp(-0.1)*v + ext - lateral;
// out = (v_new > threshold) ? 1 : 0   (straight-through forward == hard)
//
// Output is BINARY -> absmax 0.02 means zero decision flips allowed.
// fp64 accumulation, deterministic order -> matches fp64 numpy ref to ~1e-13
// (R1-R4: absmax 0.0).
//
// R5: stage1 pre-reduces 4 row-groups in LDS (partials 4->1 MiB, NCHUNK 128->32);
// reduce+spike fused into one kernel (one fewer launch, no lat round-trip).

#define PP 4096
#define BB 256

using f4 = __attribute__((ext_vector_type(4))) float;

constexpr int NCHUNK = 32;          // 128 rows per chunk
constexpr int NCTILE = 32;          // 128 cols per tile

// Stage 1: grid = 32x32 = 1024 blocks, 256 thr. Block = 128 cols x 128 rows.
// Thread owns 2 adjacent cols (float2) x 32 rows; wave w == row-group w, so
// pa[i] is wave-uniform. 4 row-group partials combined in LDS -> 1 KB write.
__global__ __launch_bounds__(256)
void lateral_partial(const float* __restrict__ w, const float* __restrict__ pa,
                     double* __restrict__ part) {
    __shared__ double sh[4 * 128];
    const int tile = blockIdx.x & (NCTILE - 1);
    const int rch  = blockIdx.x >> 5;
    const int t    = (int)threadIdx.x;
    const int cp   = t & 63;               // col-pair within tile
    const int g    = t >> 6;               // row-group (== wave id)
    const int c    = tile * 128 + cp * 2;
    const int r0   = rch * 128 + g * 32;
    double a0 = 0.0, a1 = 0.0;
#pragma unroll
    for (int k = 0; k < 32; ++k) {
        const int i = r0 + k;
        const double p = (double)pa[i];    // wave-uniform -> scalar load
        const float2 wv = *reinterpret_cast<const float2*>(w + (size_t)i * PP + c);
        a0 += p * (double)wv.x;
        a1 += p * (double)wv.y;
    }
    sh[g * 128 + cp * 2]     = a0;
    sh[g * 128 + cp * 2 + 1] = a1;
    __syncthreads();
    if (t < 128) {
        const double s = sh[t] + sh[128 + t] + sh[256 + t] + sh[384 + t];
        part[(size_t)rch * PP + tile * 128 + t] = s;   // 1 KB coalesced
    }
}

// Stage 2 (fused reduce + spike): grid = PP/16 = 256 blocks, 512 thr.
// Phase A: reduce this block's 16 columns over 32 chunks (one read/thread),
// LDS tree, subtract diagonal -> lat[16] in LDS.
// Phase B: spike for 16 cols x 256 batch rows; wave = 16 rows x 64 B coalesced.
__global__ __launch_bounds__(512)
void reduce_spike(const double* __restrict__ part, const float* __restrict__ w,
                  const float* __restrict__ pa,
                  const float* __restrict__ ext, const float* __restrict__ v,
                  const float* __restrict__ thr, float* __restrict__ out) {
    __shared__ double sh[512];
    const int t  = (int)threadIdx.x;
    const int c0 = blockIdx.x * 16;

    // Phase A: sh[chunk*16 + cj] = part[chunk][c0+cj]
    {
        const int cj    = t & 15;
        const int chunk = t >> 4;          // 0..31
        sh[t] = part[(size_t)chunk * PP + c0 + cj];
    }
    __syncthreads();
#pragma unroll
    for (int off = 256; off >= 16; off >>= 1) {
        if (t < off) sh[t] += sh[t + off];
        __syncthreads();
    }
    if (t < 16) {
        const int col = c0 + t;
        // remove self-connection: full sum included pa[col]*W[col,col]
        sh[t] -= (double)pa[col] * (double)w[(size_t)col * (PP + 1)];
    }
    __syncthreads();

    // Phase B: thread t -> col-quad q = t&3 (4 cols), row slots r, r+128.
    const int q  = t & 3;
    const int r0 = t >> 2;                 // 0..127
    const double l0 = sh[q * 4 + 0], l1 = sh[q * 4 + 1];
    const double l2 = sh[q * 4 + 2], l3 = sh[q * 4 + 3];
    const double dec = 0.90483741803595952;  // exp(-0.1) in fp64
#pragma unroll
    for (int rr = 0; rr < 2; ++rr) {
        const size_t idx = (size_t)(r0 + rr * 128) * PP + c0 + q * 4;
        const f4 e  = *reinterpret_cast<const f4*>(ext + idx);
        const f4 vv = *reinterpret_cast<const f4*>(v + idx);
        const f4 th = *reinterpret_cast<const f4*>(thr + idx);
        f4 o;
        o.x = (dec * (double)vv.x + (double)e.x - l0 > (double)th.x) ? 1.0f : 0.0f;
        o.y = (dec * (double)vv.y + (double)e.y - l1 > (double)th.y) ? 1.0f : 0.0f;
        o.z = (dec * (double)vv.z + (double)e.z - l2 > (double)th.z) ? 1.0f : 0.0f;
        o.w = (dec * (double)vv.w + (double)e.w - l3 > (double)th.w) ? 1.0f : 0.0f;
        *reinterpret_cast<f4*>(out + idx) = o;
    }
}

extern "C" void kernel_launch(void* const* d_in, const int* in_sizes, int n_in,
                              void* d_out, int out_size, void* d_ws, size_t ws_size,
                              hipStream_t stream) {
    const float* ext = (const float*)d_in[0];   // [B,P]
    const float* w   = (const float*)d_in[1];   // [P,P]
    const float* pa  = (const float*)d_in[2];   // [P]
    const float* v   = (const float*)d_in[3];   // [B,P]
    const float* thr = (const float*)d_in[4];   // [B,P]
    float* out = (float*)d_out;

    double* part = (double*)d_ws;               // NCHUNK*PP doubles = 1 MiB

    lateral_partial<<<NCTILE * NCHUNK, 256, 0, stream>>>(w, pa, part);
    reduce_spike<<<PP / 16, 512, 0, stream>>>(part, w, pa, ext, v, thr, out);
}

// Round 6
// 111.704 us; speedup vs baseline: 1.0195x; 1.0195x over previous
//
#include <hip/hip_runtime.h>

// PopulationLayer: lateral = pa @ (W with zeroed diag); v_new = exp(-0.1)*v + ext - lateral;
// out = (v_new > threshold) ? 1 : 0   (straight-through forward == hard)
//
// Output is BINARY -> absmax 0.02 means zero decision flips allowed.
// fp64 accumulation everywhere -> matches fp64 numpy ref to ~1e-13 (R1-R5: absmax 0.0).
//
// R6: revert to R4 (best measured, 111.7 us). R5's fusion + smaller partials
// were within/below noise (113.9); R3's nt hints regressed. This is the floor:
// timed window is ~85-95 us harness reset traffic at ~82% HBM peak + ~20 us of
// kernels within a few us of their 64+16 MiB streaming floor.

#define PP 4096
#define BB 256

using f4 = __attribute__((ext_vector_type(4))) float;

constexpr int ROWS_PER_CHUNK = 32;
constexpr int NCHUNK = PP / ROWS_PER_CHUNK;   // 128
constexpr int COLS_PER_TILE = 512;
constexpr int NTILE = PP / COLS_PER_TILE;     // 8

// Stage 1: deterministic partial sums. grid = NTILE*NCHUNK = 1024 blocks, 256 thr.
// Each thread owns 2 adjacent columns (float2 load), 32 rows, fully unrolled.
__global__ __launch_bounds__(256)
void lateral_partial(const float* __restrict__ w, const float* __restrict__ pa,
                     double* __restrict__ part) {
    const int tile = blockIdx.x & (NTILE - 1);
    const int rch  = blockIdx.x >> 3;               // NTILE == 8
    const int c    = tile * COLS_PER_TILE + (int)threadIdx.x * 2;
    const int r0   = rch * ROWS_PER_CHUNK;
    double a0 = 0.0, a1 = 0.0;
#pragma unroll
    for (int k = 0; k < ROWS_PER_CHUNK; ++k) {
        const int i = r0 + k;
        const double p = (double)pa[i];             // block-uniform -> scalar load
        const float2 wv = *reinterpret_cast<const float2*>(w + (size_t)i * PP + c);
        a0 += p * (double)wv.x;
        a1 += p * (double)wv.y;
    }
    *reinterpret_cast<double2*>(part + (size_t)rch * PP + c) = make_double2(a0, a1);
}

// Stage 2: reduce NCHUNK partials per column, subtract diagonal term.
// grid = PP/32 = 128 blocks; 256 thr = 32 cols x 8 chunk-groups (16 chunks each).
// 32 consecutive lanes read 32 adjacent doubles -> 256B coalesced.
__global__ __launch_bounds__(256)
void lateral_reduce(const double* __restrict__ part, const float* __restrict__ w,
                    const float* __restrict__ pa, double* __restrict__ lat) {
    __shared__ double sh[256];
    const int t   = (int)threadIdx.x;
    const int cj  = t & 31;                // col within block
    const int grp = t >> 5;                // 8 chunk-groups
    const int col = blockIdx.x * 32 + cj;
    double s = 0.0;
#pragma unroll
    for (int k = 0; k < NCHUNK / 8; ++k)   // 16 chunks per group
        s += part[(size_t)(grp * (NCHUNK / 8) + k) * PP + col];
    sh[t] = s;
    __syncthreads();
    if (t < 128) sh[t] += sh[t + 128];
    __syncthreads();
    if (t < 64)  sh[t] += sh[t + 64];
    __syncthreads();
    if (t < 32) {
        double r = sh[t] + sh[t + 32];
        // remove self-connection: the full sum included pa[col]*W[col,col]
        lat[col] = r - (double)pa[col] * (double)w[(size_t)col * (PP + 1)];
    }
}

// Stage 3: elementwise LIF + hard spike. grid = B*P/(4*256) = 1024 blocks.
__global__ __launch_bounds__(256)
void spike(const float* __restrict__ ext, const float* __restrict__ v,
           const float* __restrict__ thr, const double* __restrict__ lat,
           float* __restrict__ out) {
    const size_t t = ((size_t)blockIdx.x * 256 + threadIdx.x) * 4;
    const int j = (int)(t & (PP - 1));
    const f4 e  = *reinterpret_cast<const f4*>(ext + t);
    const f4 vv = *reinterpret_cast<const f4*>(v + t);
    const f4 th = *reinterpret_cast<const f4*>(thr + t);
    const double2 lA = *reinterpret_cast<const double2*>(lat + j);
    const double2 lB = *reinterpret_cast<const double2*>(lat + j + 2);
    const double dec = 0.90483741803595952;  // exp(-0.1) in fp64
    f4 o;
    o.x = (dec * (double)vv.x + (double)e.x - lA.x > (double)th.x) ? 1.0f : 0.0f;
    o.y = (dec * (double)vv.y + (double)e.y - lA.y > (double)th.y) ? 1.0f : 0.0f;
    o.z = (dec * (double)vv.z + (double)e.z - lB.x > (double)th.z) ? 1.0f : 0.0f;
    o.w = (dec * (double)vv.w + (double)e.w - lB.y > (double)th.w) ? 1.0f : 0.0f;
    *reinterpret_cast<f4*>(out + t) = o;
}

extern "C" void kernel_launch(void* const* d_in, const int* in_sizes, int n_in,
                              void* d_out, int out_size, void* d_ws, size_t ws_size,
                              hipStream_t stream) {
    const float* ext = (const float*)d_in[0];   // [B,P]
    const float* w   = (const float*)d_in[1];   // [P,P]
    const float* pa  = (const float*)d_in[2];   // [P]
    const float* v   = (const float*)d_in[3];   // [B,P]
    const float* thr = (const float*)d_in[4];   // [B,P]
    float* out = (float*)d_out;

    double* part = (double*)d_ws;                       // NCHUNK*PP doubles = 4 MiB
    double* lat  = part + (size_t)NCHUNK * PP;          // PP doubles = 32 KiB

    lateral_partial<<<NTILE * NCHUNK, 256, 0, stream>>>(w, pa, part);
    lateral_reduce<<<PP / 32, 256, 0, stream>>>(part, w, pa, lat);
    spike<<<(BB * PP) / (4 * 256), 256, 0, stream>>>(ext, v, thr, lat, out);
}